// Round 5
// baseline (2268.846 us; speedup 1.0000x reference)
//
#include <hip/hip_runtime.h>
#include <math.h>

// ---------------------------------------------------------------------------
// SNN forward. Round-5: rec chains striped 8(role1)/4(role0) x 128 cols,
// 256-thread WGs (4 waves), per-step FRESH exchange slots + arrive counters
// (release-add / acquire-poll, s_sleep(1)), wave-scan list rebuild.
// Round-4 showed sync (not gather) dominates: ~6us of the 7.4us step.
// ---------------------------------------------------------------------------

#define BATCH 32
#define TSTEPS 150
#define C1N 1470            // 30*7*7 (trimmed: pooled conv2 only needs 7x7)
#define ZSEQN 70
#define HID1 512
#define HID2 1024
#define K1CAT 582           // rows: [rec(512) | conv(70)]
#define K2CAT 1094          // rows: [rec(1024) | conv(70)]

#define N_Z    (BATCH*TSTEPS*ZSEQN)   // 336,000
#define N_W1T  (K1CAT*HID1)           // 297,984
#define N_W2T  (K2CAT*HID2)           // 1,120,256
#define N_ST0  (BATCH*2*C1N)          // 94,080
#define N_ST2  (BATCH*2*ZSEQN)        // 4,480

// exchange layout (u32 units)
#define SLOT1 192                     // 32 z-words + 8*2*10 fc
#define SLOT0 64                      // 16 z-words + 4*2*4 fc
#define CNT_N (64*160)                // per-(chain,step) arrive counters
#define OFF_SL1 CNT_N
#define OFF_SL0 (OFF_SL1 + 32*150*SLOT1)
#define N_EXCH (OFF_SL0 + 32*150*SLOT0)   // 1,239,040 u32 = 4.96 MB

// -------------------------------------------------------------------- K0 ---
__global__ void prep_weights(const float* __restrict__ l1_in_w,
                             const float* __restrict__ l1_rec_w,
                             const float* __restrict__ cl_in_w,
                             const float* __restrict__ cl_rec_w,
                             float* __restrict__ w1t,
                             float* __restrict__ w2t) {
    int idx = blockIdx.x * blockDim.x + threadIdx.x;
    int stride = gridDim.x * blockDim.x;
    for (int e = idx; e < N_W1T; e += stride) {
        int j = e / HID1, o = e - j * HID1;
        w1t[e] = (j < HID1) ? l1_rec_w[o * HID1 + j] : l1_in_w[o * 70 + (j - HID1)];
    }
    for (int e = idx; e < N_W2T; e += stride) {
        int j = e / HID2, o = e - j * HID2;
        w2t[e] = (j < HID2) ? cl_rec_w[o * HID2 + j] : cl_in_w[o * 70 + (j - HID2)];
    }
}

__global__ void init_exch(unsigned int* __restrict__ exch) {
    int idx = blockIdx.x * blockDim.x + threadIdx.x;
    int stride = gridDim.x * blockDim.x;
    for (int e = idx; e < CNT_N; e += stride) exch[e] = 0u;
}

// -------------------------------------------------------------------- K1 ---
__global__ __launch_bounds__(640) void conv1_pool(const float* __restrict__ x,
                                                  const float* __restrict__ w1,
                                                  const float* __restrict__ b1,
                                                  float* __restrict__ c1buf,
                                                  int t0, int CH) {
    __shared__ float img[2 * 34 * 34];
    __shared__ float w1s[30 * 2 * 49];
    __shared__ float crow[630 * 21];
    int bid = blockIdx.x;
    int b = bid / CH, tc = bid - b * CH;
    int t = t0 + tc;
    int tid = threadIdx.x;
    const float* xin = x + (size_t)(b * TSTEPS + t) * 2312;
    for (int e = tid; e < 2312; e += 640) img[e] = xin[e];
    for (int e = tid; e < 2940; e += 640) w1s[e] = w1[e];
    __syncthreads();
    if (tid < 630) {
        int oc = tid / 21, cy = tid - oc * 21;
        float acc[21];
        #pragma unroll
        for (int j = 0; j < 21; ++j) acc[j] = 0.f;
        #pragma unroll
        for (int ic = 0; ic < 2; ++ic) {
            const float* irow0 = &img[ic * 1156];
            const float* wrow = &w1s[(oc * 2 + ic) * 49];
            #pragma unroll
            for (int ky = 0; ky < 7; ++ky) {
                const float* ir = &irow0[(cy + ky) * 34];
                float r[27];
                #pragma unroll
                for (int j = 0; j < 27; ++j) r[j] = ir[j];
                #pragma unroll
                for (int kx = 0; kx < 7; ++kx) {
                    float w = wrow[ky * 7 + kx];
                    #pragma unroll
                    for (int cx = 0; cx < 21; ++cx)
                        acc[cx] = fmaf(r[cx + kx], w, acc[cx]);
                }
            }
        }
        #pragma unroll
        for (int cx = 0; cx < 21; ++cx) crow[tid * 21 + cx] = acc[cx];
    }
    __syncthreads();
    float* c1 = c1buf + (size_t)bid * C1N;
    for (int p = tid; p < C1N; p += 640) {
        int oc = p / 49; int r = p - oc * 49; int py = r / 7, px = r - py * 7;
        float m = -1e30f;
        #pragma unroll
        for (int dy = 0; dy < 3; ++dy) {
            int rowid = oc * 21 + 3 * py + dy;
            #pragma unroll
            for (int dx = 0; dx < 3; ++dx)
                m = fmaxf(m, crow[rowid * 21 + 3 * px + dx]);
        }
        c1[p] = m + b1[oc];
    }
}

// -------------------------------------------------------------------- K2 ---
__global__ __launch_bounds__(320) void conv2_chain(const float* __restrict__ w2,
                                                   const float* __restrict__ b2,
                                                   const float* __restrict__ c1buf,
                                                   float* __restrict__ zbuf,
                                                   const float* __restrict__ st0_in,
                                                   float* __restrict__ st0_out,
                                                   const float* __restrict__ st2_in,
                                                   float* __restrict__ st2_out,
                                                   int t0, int CH) {
    int bid = blockIdx.x;
    int b = bid >> 3, w = bid & 7;
    int ocStart = w * 9;
    int nOc = (w == 7) ? 7 : 9;
    int tid = threadIdx.x;
    __shared__ float v0[C1N], i0[C1N], z0[C1N];
    __shared__ float w2s[9 * 750];
    __shared__ float part[9 * 30 * 9];
    __shared__ float red[81];
    for (int e = tid; e < nOc * 750; e += 320) w2s[e] = w2[ocStart * 750 + e];
    float v2 = 0.f, i2 = 0.f;
    if (t0 == 0) {
        for (int e = tid; e < C1N; e += 320) { v0[e] = 0.f; i0[e] = 0.f; }
    } else {
        const float* s0 = st0_in + (size_t)b * 2 * C1N;
        for (int e = tid; e < C1N; e += 320) { v0[e] = s0[e]; i0[e] = s0[C1N + e]; }
        if (tid < nOc) {
            v2 = st2_in[b * ZSEQN + ocStart + tid];
            i2 = st2_in[BATCH * ZSEQN + b * ZSEQN + ocStart + tid];
        }
    }
    float bias2 = (tid < nOc) ? b2[ocStart + tid] : 0.f;
    __syncthreads();
    const float* c1b = c1buf + (size_t)b * CH * C1N;
    float* zs = zbuf + (size_t)b * TSTEPS * ZSEQN;
    int nConv = nOc * 30;
    for (int tc = 0; tc < CH; ++tc) {
        const float* c1t = c1b + (size_t)tc * C1N;
        for (int e = tid; e < C1N; e += 320) {
            float v = v0[e], i = i0[e];
            float vd = v + 0.1f * (i - v);
            float id = i - 0.2f * i;
            bool sp = (vd > 1.0f);
            v0[e] = sp ? 0.f : vd;
            i0[e] = id + c1t[e];
            z0[e] = sp ? 1.f : 0.f;
        }
        __syncthreads();
        if (tid < nConv) {
            int ol = tid / 30, ic = tid - ol * 30;
            float zw[49];
            #pragma unroll
            for (int j = 0; j < 49; ++j) zw[j] = z0[ic * 49 + j];
            float a[9];
            #pragma unroll
            for (int p = 0; p < 9; ++p) a[p] = 0.f;
            const float* wb = &w2s[ol * 750 + ic * 25];
            #pragma unroll
            for (int ky = 0; ky < 5; ++ky)
                #pragma unroll
                for (int kx = 0; kx < 5; ++kx) {
                    float wv = wb[ky * 5 + kx];
                    #pragma unroll
                    for (int cy = 0; cy < 3; ++cy)
                        #pragma unroll
                        for (int cx = 0; cx < 3; ++cx)
                            a[cy * 3 + cx] = fmaf(zw[(cy + ky) * 7 + cx + kx], wv, a[cy * 3 + cx]);
                }
            #pragma unroll
            for (int p = 0; p < 9; ++p) part[tid * 9 + p] = a[p];
        }
        __syncthreads();
        if (tid < nOc * 9) {
            int ol = tid / 9, pos = tid - ol * 9;
            float s = 0.f;
            for (int ic = 0; ic < 30; ++ic) s += part[(ol * 30 + ic) * 9 + pos];
            red[tid] = s;
        }
        __syncthreads();
        if (tid < nOc) {
            float m = -1e30f;
            #pragma unroll
            for (int p = 0; p < 9; ++p) m = fmaxf(m, red[tid * 9 + p]);
            float inp = m + bias2;
            float vd = v2 + 0.1f * (i2 - v2);
            float id = i2 - 0.2f * i2;
            bool sp = (vd > 1.0f);
            v2 = sp ? 0.f : vd;
            i2 = id + inp;
            zs[(size_t)(t0 + tc) * ZSEQN + ocStart + tid] = sp ? 1.f : 0.f;
        }
        __syncthreads();
    }
    if (w == 0) {
        float* s0 = st0_out + (size_t)b * 2 * C1N;
        for (int e = tid; e < C1N; e += 320) { s0[e] = v0[e]; s0[C1N + e] = i0[e]; }
    }
    if (tid < nOc) {
        st2_out[b * ZSEQN + ocStart + tid] = v2;
        st2_out[BATCH * ZSEQN + b * ZSEQN + ocStart + tid] = i2;
    }
}

// -------------------------------------------------------------------- K3 ---
__device__ __forceinline__ float4 f4add(float4 a, const float4 b) {
    a.x += b.x; a.y += b.y; a.z += b.z; a.w += b.w; return a;
}
__device__ __forceinline__ void ast(unsigned int* p, unsigned int v) {
    __hip_atomic_store(p, v, __ATOMIC_RELAXED, __HIP_MEMORY_SCOPE_AGENT);
}
__device__ __forceinline__ unsigned int ald(unsigned int* p) {
    return __hip_atomic_load(p, __ATOMIC_RELAXED, __HIP_MEMORY_SCOPE_AGENT);
}

// One 128-col stripe of one chain per WG (256 threads, 4 waves).
template <int ROLE>
__device__ __forceinline__ void rec_stripe_body(
        int b, int sid,
        const float* __restrict__ fcw,
        const float* __restrict__ zbuf,
        const float* __restrict__ catT,
        unsigned int* __restrict__ cnt,      // per-step counters (stride 1)
        unsigned int* __restrict__ slots,    // per-step slots (stride SLOT)
        float* __restrict__ out,
        float* fcwl, float* part, unsigned short* list,
        unsigned int* maskw, unsigned int* wprefix, float* fcbuf, float* mvals) {
    constexpr int N    = ROLE ? HID2 : HID1;
    constexpr int K    = ROLE ? K2CAT : K1CAT;
    constexpr int R    = ROLE ? 10 : 4;
    constexpr int CS   = ROLE ? 8 : 4;
    constexpr int NW   = N / 32;
    constexpr int NWT  = NW + 3;
    constexpr int SLOT = ROLE ? SLOT1 : SLOT0;
    constexpr int COLS = 128, PSTR = 132;
    constexpr int N4   = N / 4;

    const int t = threadIdx.x;
    const int lane = t & 63, wv = t >> 6;
    const int aid = t >> 5, qid = t & 31;   // 8 A-slices x 32 quads
    const int base = sid * 32 + qid;        // quad offset within a row

    for (int e = t; e < R * COLS; e += 256)
        fcwl[e] = fcw[(e >> 7) * N + sid * COLS + (e & 127)];

    const float* zsb = zbuf + (size_t)b * TSTEPS * ZSEQN;
    const float4* __restrict__ catT4 = (const float4*)catT;

    float v = 0.f, iacc = 0.f;
    float vli = 0.f, ili = 0.f, rmax = -1e30f;

    // ---- initial list: rec bits 0, conv bits from zsb[0] ----
    if (t < NW) maskw[t] = 0u;
    {
        float zc = (t < 70) ? zsb[t] : 0.f;
        unsigned long long mc = __ballot(zc != 0.f);
        if (lane == 0) {
            if (wv == 0) { maskw[NW] = (unsigned)mc; maskw[NW + 1] = (unsigned)(mc >> 32); }
            else if (wv == 1) { maskw[NW + 2] = (unsigned)(mc & 0x3full); }
        }
    }
    __syncthreads();
    if (wv == 0) {
        unsigned val = (lane < NWT) ? __popc(maskw[lane]) : 0u;
        #pragma unroll
        for (int d = 1; d < 64; d <<= 1) {
            unsigned u = __shfl_up(val, d);
            if (lane >= d) val += u;
        }
        if (lane < NWT) wprefix[lane + 1] = val;
        if (lane == 0) wprefix[0] = 0u;
    }
    __syncthreads();
    int A = wprefix[NWT];
    for (int jj = t; jj < K; jj += 256) {
        unsigned m = maskw[jj >> 5];
        if ((m >> (jj & 31)) & 1u)
            list[wprefix[jj >> 5] + __popc(m & ((1u << (jj & 31)) - 1u))] = (unsigned short)jj;
    }
    __syncthreads();

    for (int tt = 0; tt < TSTEPS; ++tt) {
        float znext = (t < 70 && tt + 1 < TSTEPS) ? zsb[(size_t)(tt + 1) * ZSEQN + t] : 0.f;
        // ---- stripe gather over active rows ----
        float4 s0 = {0.f, 0.f, 0.f, 0.f}, s1 = s0, s2 = s0, s3 = s0;
        int idx = aid;
        for (; idx + 24 < A; idx += 32) {
            s0 = f4add(s0, catT4[(size_t)list[idx]      * N4 + base]);
            s1 = f4add(s1, catT4[(size_t)list[idx + 8]  * N4 + base]);
            s2 = f4add(s2, catT4[(size_t)list[idx + 16] * N4 + base]);
            s3 = f4add(s3, catT4[(size_t)list[idx + 24] * N4 + base]);
        }
        for (; idx < A; idx += 8) s0 = f4add(s0, catT4[(size_t)list[idx] * N4 + base]);
        s0 = f4add(f4add(s0, s1), f4add(s2, s3));
        *(float4*)(part + aid * PSTR + 4 * qid) = s0;
        __syncthreads();                                   // B1: part ready
        float znew = 0.f;
        if (t < COLS) {
            float cur = 0.f;
            #pragma unroll
            for (int a = 0; a < 8; ++a) cur += part[a * PSTR + t];
            float vd = v + 0.1f * (iacc - v);
            float id = iacc - 0.2f * iacc;
            bool sp = (vd > 0.4f);
            znew = sp ? 1.f : 0.f;
            v = sp ? 0.f : vd;
            iacc = id + cur;
        }
        unsigned int* slot = slots + (size_t)tt * SLOT;
        unsigned long long mz = __ballot(znew != 0.f);
        if (lane == 0 && wv < 2) {
            ast(slot + sid * 4 + wv * 2,     (unsigned)mz);
            ast(slot + sid * 4 + wv * 2 + 1, (unsigned)(mz >> 32));
        }
        // fc partials, stored per (stripe, wave)
        #pragma unroll
        for (int k = 0; k < R; ++k) {
            float c = (t < COLS && znew != 0.f) ? fcwl[k * COLS + t] : 0.f;
            #pragma unroll
            for (int off = 32; off; off >>= 1) c += __shfl_xor(c, off);
            if (lane == 0 && wv < 2)
                ast(slot + NW + (sid * 2 + wv) * R + k, __float_as_uint(c));
        }
        __syncthreads();                     // B2: every wave's stores drained
        if (t == 0) {
            __hip_atomic_fetch_add(cnt + tt, 1u, __ATOMIC_RELEASE, __HIP_MEMORY_SCOPE_AGENT);
            while (__hip_atomic_load(cnt + tt, __ATOMIC_ACQUIRE, __HIP_MEMORY_SCOPE_AGENT) < (unsigned)CS)
                __builtin_amdgcn_s_sleep(1);
        }
        __syncthreads();                                   // B3: all stripes arrived
        if (t < NW) maskw[t] = ald(slot + t);
        {
            unsigned long long mc = __ballot(znext != 0.f);
            if (lane == 0) {
                if (wv == 0) { maskw[NW] = (unsigned)mc; maskw[NW + 1] = (unsigned)(mc >> 32); }
                else if (wv == 1) { maskw[NW + 2] = (unsigned)(mc & 0x3full); }
            }
        }
        if (sid == 0 && t < CS * 2 * R) fcbuf[t] = __uint_as_float(ald(slot + NW + t));
        __syncthreads();                                   // B4: maskw + fcbuf
        if (wv == 0) {
            unsigned val = (lane < NWT) ? __popc(maskw[lane]) : 0u;
            #pragma unroll
            for (int d = 1; d < 64; d <<= 1) {
                unsigned u = __shfl_up(val, d);
                if (lane >= d) val += u;
            }
            if (lane < NWT) wprefix[lane + 1] = val;
            if (lane == 0) wprefix[0] = 0u;
        }
        __syncthreads();                                   // B5: wprefix
        if (sid == 0 && t < R) {
            float inp = 0.f;
            #pragma unroll
            for (int u = 0; u < CS * 2; ++u) inp += fcbuf[u * R + t];
            float vn = vli + 0.1f * (ili - vli);
            ili = ili - 0.2f * ili + inp;
            vli = vn;
            rmax = fmaxf(rmax, vn);
        }
        A = wprefix[NWT];
        for (int jj = t; jj < K; jj += 256) {
            unsigned m = maskw[jj >> 5];
            if ((m >> (jj & 31)) & 1u)
                list[wprefix[jj >> 5] + __popc(m & ((1u << (jj & 31)) - 1u))] = (unsigned short)jj;
        }
        __syncthreads();                                   // B6: list ready
    }

    if (sid == 0) {
        if (ROLE == 1) {
            if (t < 10) mvals[t] = rmax;
            __syncthreads();
            if (t < 10) {
                float M = -1e30f;
                #pragma unroll
                for (int k = 0; k < 10; ++k) M = fmaxf(M, mvals[k]);
                float s = 0.f;
                #pragma unroll
                for (int k = 0; k < 10; ++k) s += expf(mvals[k] - M);
                out[BATCH * 4 + b * 10 + t] = mvals[t] - M - logf(s);
            }
        } else {
            if (t < 4) out[b * 4 + t] = rmax;
        }
    }
}

__global__ __launch_bounds__(256) void rec_stripe(const float* __restrict__ fc_out_w,
                                                  const float* __restrict__ cl_fc_w,
                                                  const float* __restrict__ zbuf,
                                                  const float* __restrict__ w1t,
                                                  const float* __restrict__ w2t,
                                                  unsigned int* __restrict__ exch,
                                                  float* __restrict__ out) {
    __shared__ float fcwl[1280];
    __shared__ float part[1056];
    __shared__ unsigned short list[K2CAT];
    __shared__ unsigned int maskw[36];
    __shared__ unsigned int wprefix[36];
    __shared__ float fcbuf[160];
    __shared__ float mvals[10];

    int bid = blockIdx.x;
    if (bid < 256) {
        int b = bid >> 3, sid = bid & 7;
        rec_stripe_body<1>(b, sid, cl_fc_w, zbuf, w2t,
                           exch + (size_t)b * 160,
                           exch + OFF_SL1 + (size_t)b * 150 * SLOT1,
                           out, fcwl, part, list, maskw, wprefix, fcbuf, mvals);
    } else {
        int idx = bid - 256;
        int b = idx >> 2, sid = idx & 3;
        rec_stripe_body<0>(b, sid, fc_out_w, zbuf, w1t,
                           exch + (size_t)(32 + b) * 160,
                           exch + OFF_SL0 + (size_t)b * 150 * SLOT0,
                           out, fcwl, part, list, maskw, wprefix, fcbuf, mvals);
    }
}

// ---------------------------------------------------------------------------
extern "C" void kernel_launch(void* const* d_in, const int* in_sizes, int n_in,
                              void* d_out, int out_size, void* d_ws, size_t ws_size,
                              hipStream_t stream) {
    const float* x        = (const float*)d_in[0];
    const float* w1       = (const float*)d_in[1];
    const float* b1       = (const float*)d_in[2];
    const float* w2       = (const float*)d_in[3];
    const float* b2       = (const float*)d_in[4];
    const float* l1_in_w  = (const float*)d_in[5];
    const float* l1_rec_w = (const float*)d_in[6];
    const float* fc_out_w = (const float*)d_in[7];
    const float* cl_in_w  = (const float*)d_in[8];
    const float* cl_rec_w = (const float*)d_in[9];
    const float* cl_fc_w  = (const float*)d_in[10];
    float* out = (float*)d_out;
    float* ws  = (float*)d_ws;

    size_t base = (size_t)N_Z + N_W1T + N_W2T + N_EXCH + 2 * (N_ST0 + N_ST2);
    size_t avail = ws_size / 4;
    static const int divs[] = {150, 75, 50, 30, 25, 15, 10, 6, 5, 3, 2, 1};
    int CH = 1;
    for (int i = 0; i < 12; ++i) {
        size_t need = base + (size_t)BATCH * divs[i] * C1N;
        if (need <= avail) { CH = divs[i]; break; }
    }
    float* zbuf = ws;
    float* w1t  = zbuf + N_Z;
    float* w2t  = w1t + N_W1T;
    unsigned int* exch = (unsigned int*)(w2t + N_W2T);
    float* st0a = w2t + N_W2T + N_EXCH;
    float* st0b = st0a + N_ST0;
    float* st2a = st0b + N_ST0;
    float* st2b = st2a + N_ST2;
    float* c1buf = st2b + N_ST2;

    prep_weights<<<dim3(512), dim3(256), 0, stream>>>(l1_in_w, l1_rec_w,
                                                      cl_in_w, cl_rec_w, w1t, w2t);
    init_exch<<<dim3(10), dim3(1024), 0, stream>>>(exch);
    int nChunks = TSTEPS / CH;
    for (int c = 0; c < nChunks; ++c) {
        int t0 = c * CH;
        int par = c & 1;
        const float* s0i = par ? st0b : st0a;
        float*       s0o = par ? st0a : st0b;
        const float* s2i = par ? st2b : st2a;
        float*       s2o = par ? st2a : st2b;
        conv1_pool<<<dim3(BATCH * CH), dim3(640), 0, stream>>>(x, w1, b1, c1buf, t0, CH);
        conv2_chain<<<dim3(256), dim3(320), 0, stream>>>(w2, b2, c1buf, zbuf,
                                                         s0i, s0o, s2i, s2o, t0, CH);
    }
    rec_stripe<<<dim3(384), dim3(256), 0, stream>>>(fc_out_w, cl_fc_w, zbuf,
                                                    w1t, w2t, exch, out);
}